// Round 7
// baseline (57.813 us; speedup 1.0000x reference)
//
#include <hip/hip_runtime.h>

#define IN_F   4096
#define KSZ    16
#define LOCAL  64
#define FOLDN  4081   // (4096 - 16)/1 + 1
#define BATCH  256

#define F_TILE 16     // folds per block
#define B_SPLIT 8     // blocks along batch
#define B_PER  (BATCH / B_SPLIT)  // 32 batches per block
#define XROW   36     // padded row stride (floats): 16B-aligned

typedef float f32x4 __attribute__((ext_vector_type(4)));

__global__ __launch_bounds__(256)
void LocalLinear_kernel(const float* __restrict__ x,
                        const float* __restrict__ w,
                        const float* __restrict__ bias,
                        float* __restrict__ out) {
    // transposed x tile: xs[j][bi] = x[b0+bi][f0+j]
    __shared__ float xs[32][XROW];

    // XCD swizzle: all 8 b-split sharers of each weight slice run on the
    // same XCD -> slice lands in that L2 once (2MB weight per XCD).
    const int lin = blockIdx.x;              // 0..2047
    const int xcd = lin & 7;
    const int i   = lin >> 3;                // 0..255 within XCD
    const int fx  = (xcd << 5) | (i & 31);   // f-tile 0..255
    const int by  = i >> 5;                  // b-split 0..7

    const int t  = threadIdx.x;
    const int f0 = fx * F_TILE;
    const int b0 = by * B_PER;

    // ---- stage x tile (coalesced global read over j; transposed LDS write) ----
    for (int idx = t; idx < 32 * B_PER; idx += 256) {
        const int j  = idx >> 5;          // column (fold offset) 0..31
        const int bi = idx & 31;          // batch within tile
        const int col = f0 + j;
        xs[j][bi] = (col < IN_F) ? x[(size_t)(b0 + bi) * IN_F + col] : 0.0f;
    }

    const int l4 = t & 15;    // which float4 of the 64 locals
    const int fi = t >> 4;    // 0..15 within the f tile
    const int f  = f0 + fi;
    const bool valid = (f < FOLDN);

    // ---- weight fragment in registers: w[f][k][4*l4 .. 4*l4+3], k=0..15 ----
    f32x4 wf[KSZ];
    f32x4 bv = (f32x4)(0.f);
    if (valid) {
        const f32x4* wp = (const f32x4*)(w + (size_t)f * (KSZ * LOCAL) + l4 * 4);
        #pragma unroll
        for (int k = 0; k < KSZ; ++k)
            wf[k] = wp[(size_t)k * (LOCAL / 4)];   // stride 64 floats
        bv = *(const f32x4*)(bias + (size_t)f * LOCAL + l4 * 4);
    }

    __syncthreads();

    if (!valid) return;   // no barriers after this point

    float* outp = out + ((size_t)b0 * FOLDN + f) * LOCAL + l4 * 4;
    const size_t ostride = (size_t)FOLDN * LOCAL;

    for (int bi0 = 0; bi0 < B_PER; bi0 += 4) {
        f32x4 a0 = bv, a1 = bv, a2 = bv, a3 = bv;
        #pragma unroll
        for (int k = 0; k < KSZ; ++k) {
            // one aligned b128 read: x for 4 batches at fold-column fi+k
            const f32x4 xv = *(const f32x4*)&xs[fi + k][bi0];
            a0 += xv.x * wf[k];
            a1 += xv.y * wf[k];
            a2 += xv.z * wf[k];
            a3 += xv.w * wf[k];
        }
        float* p = outp + (size_t)bi0 * ostride;
        *(f32x4*)p = a0; p += ostride;
        *(f32x4*)p = a1; p += ostride;
        *(f32x4*)p = a2; p += ostride;
        *(f32x4*)p = a3;
    }
}

extern "C" void kernel_launch(void* const* d_in, const int* in_sizes, int n_in,
                              void* d_out, int out_size, void* d_ws, size_t ws_size,
                              hipStream_t stream) {
    const float* x    = (const float*)d_in[0];
    const float* w    = (const float*)d_in[1];
    const float* bias = (const float*)d_in[2];
    float* out = (float*)d_out;

    dim3 grid(256 * B_SPLIT);   // 2048 linear, swizzled in-kernel
    dim3 block(256);
    LocalLinear_kernel<<<grid, block, 0, stream>>>(x, w, bias, out);
}